// Round 13
// baseline (17814.557 us; speedup 1.0000x reference)
//
#include <hip/hip_runtime.h>
#include <hip/hip_bf16.h>

// 2-layer GRU decoder, persistent MFMA kernel. B=128, T=1024, H=200.
// 8 batch-groups (16 batch each) x 16 hidden-slice blocks = 128 blocks.
// Weights live in REGISTERS as bf16 hi/lo MFMA A-fragments; per-step GEMM via
// mfma_f32_16x16x32_bf16 x3 (hi*hi + hi*lo + lo*hi) for fp32-grade precision.
// R16 = R13 (2926us, proven) + same-XCD L2 fast path gated by an EMPIRICAL
// visibility handshake (not HW_REG_XCC_ID -- R1-R3's mistake):
//   startup: 3 rounds of {plain-store token; peers sc0-load it} with bounded
//   deadlines. Cross-XCD peers cannot see re-dirtied L2 lines (write-back L2,
//   quiet traffic) -> test fails -> fallback. Verdicts published system-scope;
//   decision = AND over the group's 16 verdicts -> globally consistent.
// Fast path: h exchange via plain stores (land in XCD L2) + sc0 dwordx4
// staging loads (bypass L1, hit shared L2, ~200cy vs ~700-1000cy LLC); flags
// likewise. Fallback: R13-verbatim. All per-step polls bounded (fail-visible).
// Ledger: R3 3157 -> R8 2998 (flag barrier) -> R13 2926 (store remap).
// Lessons held: scope no lever (R9); RMWs pipeline (R8); load-side layout
// untouchable (R11); staging RT-bound not issue-bound (R14); poll = one
// sleepy wave/block (R7/R10/R12); single-block multiplexing serializes (R15).

#define TT 1024
#define HH 200
#define NB 16
#define HS 13
#define KP 232   // hB row stride in ushorts; 464 B = 29*16 -> b128-aligned

typedef __attribute__((ext_vector_type(8))) short short8;
typedef __attribute__((ext_vector_type(4))) short short4v;
typedef __attribute__((ext_vector_type(4))) float f32x4;
typedef __attribute__((ext_vector_type(4))) uint uint4v;

__device__ __forceinline__ float sigm(float v) { return 1.0f / (1.0f + __expf(-v)); }
__device__ __forceinline__ float tanh_fast(float v) {
  float e = __expf(-2.0f * v);
  return (1.0f - e) / (1.0f + e);
}
__device__ __forceinline__ uint llc_load_u32(const uint* p) {
  return __hip_atomic_load(p, __ATOMIC_RELAXED, __HIP_MEMORY_SCOPE_SYSTEM);
}
__device__ __forceinline__ void llc_store_u32(uint* p, uint v) {
  __hip_atomic_store(p, v, __ATOMIC_RELAXED, __HIP_MEMORY_SCOPE_SYSTEM);
}
// Fast-path primitives (used only after the handshake PROVES visibility):
// plain store -> lands in the XCD's write-back L2 (L1 is write-through);
// sc0 load -> bypass own L1, read the shared L2.
__device__ __forceinline__ void wg_store_u32(uint* p, uint v) {
  __hip_atomic_store(p, v, __ATOMIC_RELAXED, __HIP_MEMORY_SCOPE_WORKGROUP);
}
__device__ __forceinline__ uint l2_load_u32(const uint* p) {
  uint r;
  asm volatile("global_load_dword %0, %1, off sc0\n\ts_waitcnt vmcnt(0)"
               : "=v"(r) : "v"(p) : "memory");
  return r;
}
__device__ __forceinline__ float bfu2f(ushort u) {
  return __uint_as_float(((uint)u) << 16);
}
__device__ __forceinline__ ushort f2bfu(float f) {
  __hip_bfloat16 b = __float2bfloat16(f);
  return *(ushort*)&b;
}
__device__ __forceinline__ uint packf(float h) {
  ushort hi = f2bfu(h);
  float  fh = bfu2f(hi);
  ushort lo = f2bfu(h - fh);
  return (uint)hi | ((uint)lo << 16);
}

__global__ __launch_bounds__(256, 1) void gru2_mfma(
    const float* __restrict__ x,
    const float* __restrict__ Wih0, const float* __restrict__ Whh0,
    const float* __restrict__ bih0, const float* __restrict__ bhh0,
    const float* __restrict__ Wih1, const float* __restrict__ Whh1,
    const float* __restrict__ bih1, const float* __restrict__ bhh1,
    const float* __restrict__ Wfc,  const float* __restrict__ bfc,
    float* __restrict__ out,
    uint* __restrict__ h0g, uint* __restrict__ h1g, uint* __restrict__ syncp)
{
  __shared__ __align__(16) ushort hBh[2][NB][KP];
  __shared__ __align__(16) ushort hBl[2][NB][KP];
  __shared__ float D[117][17];
  __shared__ float Wi0t[8][39];
  __shared__ float bi0[39], bh0[39], bi1[39], bh1[39], bfs[4];
  __shared__ float xc[NB][8];
  __shared__ int s_fast, s_hsok;

  const int tid  = threadIdx.x;
  const int wave = tid >> 6;
  const int lane = tid & 63;
  const int m15  = lane & 15;
  const int q    = lane >> 4;

  const int g  = blockIdx.x & 7;    // batch-group
  const int s  = blockIdx.x >> 3;   // hidden-slice
  const int b0 = g * NB;
  const int j0 = s * HS;
  const int hs = (HH - j0 < HS) ? (HH - j0) : HS;
  const int th   = 3 * hs;
  const int h0r  = 6 * hs;
  const int T0   = (h0r + 15) >> 4;
  const int NT   = T0 + ((th + 15) >> 4);
  const bool isOut = (s == 15);

  // sync: flags @syncp (512 u32, flag(g,s)=g*64+s*4, R13-verbatim),
  // handshake tokens @+512 (128 x stride16), verdicts @+2560 (128 x stride4).
  uint* flags = syncp;
  uint* tok   = syncp + 512;
  uint* verd  = syncp + 2560;

  // ---- one-time: weight A-fragments into registers (hi/lo bf16) ----
  short8 Ah[2][7], Al[2][7];
  #pragma unroll
  for (int mt = 0; mt < 2; ++mt) {
    const int T = wave * 2 + mt;
    const bool fc  = isOut && (wave == 2) && (mt == 0);
    const bool val = fc || (T < NT);
    #pragma unroll
    for (int kt = 0; kt < 7; ++kt) {
      short8 vh = {0,0,0,0,0,0,0,0}, vl = {0,0,0,0,0,0,0,0};
      #pragma unroll
      for (int j = 0; j < 8; ++j) {
        const int k = kt * 32 + q * 8 + j;
        float w = 0.0f;
        if (val && k < HH) {
          if (fc) {
            if (m15 < 4) w = Wfc[m15 * HH + k];
          } else {
            const int p = T * 16 + m15;
            int r = -1;
            if (p < h0r) r = p;
            else if (p >= T0 * 16 && (p - T0 * 16) < th) r = h0r + (p - T0 * 16);
            if (r >= 0) {
              const int m  = r / th, rr = r - m * th;
              const int qq = rr / hs, jj = rr - qq * hs;
              const float* src = (m == 0) ? Whh0 : ((m == 1) ? Wih1 : Whh1);
              w = src[(qq * HH + j0 + jj) * HH + k];
            }
          }
        }
        const ushort uh = f2bfu(w);
        const ushort ul = f2bfu(w - bfu2f(uh));
        vh[j] = (short)uh; vl[j] = (short)ul;
      }
      Ah[mt][kt] = vh; Al[mt][kt] = vl;
    }
  }

  // ---- one-time: small LDS tables ----
  for (int u = tid; u < th * 8; u += 256) {
    int rr = u >> 3, c = u & 7;
    int qq = rr / hs, jj = rr - qq * hs;
    Wi0t[c][rr] = Wih0[(qq * HH + j0 + jj) * 8 + c];
  }
  for (int u = tid; u < th; u += 256) {
    int qq = u / hs, jj = u - qq * hs;
    int grow = qq * HH + j0 + jj;
    bi0[u] = bih0[grow]; bh0[u] = bhh0[grow];
    bi1[u] = bih1[grow]; bh1[u] = bhh1[grow];
  }
  if (tid < 4) bfs[tid] = bfc[tid];
  for (int u = tid; u < 2 * NB * KP / 2; u += 256) ((uint*)hBh)[u] = 0;
  for (int u = tid; u < 2 * NB * KP / 2; u += 256) ((uint*)hBl)[u] = 0;
  if (tid < 128 && (tid & 7) >= 4)   // emotion columns: t-invariant
    xc[tid >> 3][tid & 7] = x[(b0 + (tid >> 3)) * TT * 8 + (tid & 7)];
  __syncthreads();

  // ---- EMPIRICAL visibility handshake (3 rounds of fresh tokens) ----
  // Passing requires peers to see each re-dirtied token via sc0 within the
  // deadline -- only possible when all 16 group blocks share one L2.
  int hsv = 1;
  for (int r = 0; r < 3; ++r) {
    if (tid == 0) wg_store_u32(&tok[blockIdx.x * 16], (uint)(r + 1));
    if (wave == 0) {
      int ok = 0;
      const uint* tp = &tok[(g + (lane & 15) * 8) * 16];
      for (int it = 0; it < 30000; ++it) {
        const uint v = (lane < 16) ? l2_load_u32(tp) : (uint)(r + 1);
        if (__all((int)(v >= (uint)(r + 1)))) { ok = 1; break; }
        __builtin_amdgcn_s_sleep(2);
      }
      if (lane == 0) s_hsok = ok;
    }
    __syncthreads();
    hsv &= s_hsok;
    __syncthreads();
  }
  if (tid == 0) llc_store_u32(&verd[blockIdx.x * 4], hsv ? 2u : 1u);
  if (wave == 0) {
    const uint* vp = &verd[(g + (lane & 15) * 8) * 4];
    uint v = 2u;
    // Co-residency is proven (baseline's per-step barrier passes), so all
    // verdicts WILL arrive; generous bound only as a hang guard.
    for (int it = 0; it < 5000000; ++it) {
      v = (lane < 16) ? llc_load_u32(vp) : 2u;
      if (__all((int)(v >= 1u))) break;
      __builtin_amdgcn_s_sleep(4);
    }
    const int fast = __all((int)(((lane < 16) ? v : 2u) == 2u));
    if (lane == 0) s_fast = fast;
  }
  __syncthreads();
  const bool fastp = (s_fast != 0);

  // ---- fast-path staging chunk pointers (dwordx4, both parities) ----
  // 1600 chunks cover 2 states x 16 b x 50 k-quads. Clamped chunks (u>=1600)
  // redundantly re-load chunk 0; unpack guards on the original u.
  const uint *qe0, *qe1, *qe2, *qe3, *qe4, *qe5, *qe6;
  const uint *qo0, *qo1, *qo2, *qo3, *qo4, *qo5, *qo6;
  {
    auto cp = [&](int i, int par) -> const uint* {
      int u = tid + i * 256; if (u >= 1600) u = 0;
      const int st = u / 800, rem = u - st * 800;
      const int b = rem / 50, kc = rem - b * 50;
      // h0src parity (t+1)&1, h1src parity t&1 (par = t&1)
      const uint* base = st ? (h1g + par * 25600) : (h0g + (par ? 0 : 25600));
      return base + (b0 + b) * HH + kc * 4;
    };
    qe0 = cp(0,0); qe1 = cp(1,0); qe2 = cp(2,0); qe3 = cp(3,0);
    qe4 = cp(4,0); qe5 = cp(5,0); qe6 = cp(6,0);
    qo0 = cp(0,1); qo1 = cp(1,1); qo2 = cp(2,1); qo3 = cp(3,1);
    qo4 = cp(4,1); qo5 = cp(5,1); qo6 = cp(6,1);
  }

  // Gate-combine remap (R13, proven): cb = tid/hs, cj = tid%hs.
  const int gt = 16 * hs;
  const int cb = tid / hs;
  const int cj = tid - cb * hs;
  const int xb = tid >> 3, xcc7 = tid & 7;

  for (int t = 0; t <= TT + 1; ++t) {
    // ---- hoist teacher-forcing x load ----
    float xtf = 1.0f;
    if (tid < 128 && xcc7 < 4 && t > 0 && t < TT)
      xtf = x[((b0 + xb) * TT + (t - 1)) * 8 + xcc7];

    // ---- stage h0(t-1), h1(t-2) ----
    if (fastp) {
      const bool odd = (t & 1);
      const uint *a0 = odd ? qo0 : qe0, *a1 = odd ? qo1 : qe1,
                 *a2 = odd ? qo2 : qe2, *a3 = odd ? qo3 : qe3,
                 *a4 = odd ? qo4 : qe4, *a5 = odd ? qo5 : qe5,
                 *a6 = odd ? qo6 : qe6;
      uint4v r0, r1, r2, r3, r4, r5, r6;
      asm volatile(
        "global_load_dwordx4 %0, %7, off sc0\n\t"
        "global_load_dwordx4 %1, %8, off sc0\n\t"
        "global_load_dwordx4 %2, %9, off sc0\n\t"
        "global_load_dwordx4 %3, %10, off sc0\n\t"
        "global_load_dwordx4 %4, %11, off sc0\n\t"
        "global_load_dwordx4 %5, %12, off sc0\n\t"
        "global_load_dwordx4 %6, %13, off sc0\n\t"
        "s_waitcnt vmcnt(0)"
        : "=&v"(r0), "=&v"(r1), "=&v"(r2), "=&v"(r3),
          "=&v"(r4), "=&v"(r5), "=&v"(r6)
        : "v"(a0), "v"(a1), "v"(a2), "v"(a3), "v"(a4), "v"(a5), "v"(a6)
        : "memory");
      auto unpack = [&](int i, uint4v tv) {
        const int u = tid + i * 256;
        if (u < 1600) {
          const int st = u / 800, rem = u - st * 800;
          const int b = rem / 50, kc = rem - b * 50;
          const int k = kc * 4;
          short4v hi, lo;
          #pragma unroll
          for (int j = 0; j < 4; ++j) {
            hi[j] = (short)(tv[j] & 0xffffu);
            lo[j] = (short)(tv[j] >> 16);
          }
          *(short4v*)&hBh[st][b][k] = hi;
          *(short4v*)&hBl[st][b][k] = lo;
        }
      };
      unpack(0, r0); unpack(1, r1); unpack(2, r2); unpack(3, r3);
      unpack(4, r4); unpack(5, r5); unpack(6, r6);
    } else {
      const uint* h0src = h0g + ((t + 1) & 1) * (128 * HH);
      const uint* h1src = h1g + (t & 1) * (128 * HH);
      uint tmp[25];
      #pragma unroll
      for (int i = 0; i < 25; ++i) {
        const int u  = tid + i * 256;
        const int st = u / 3200, rem = u - st * 3200;
        const int b  = rem / 200, k = rem - b * 200;
        tmp[i] = llc_load_u32(&(st ? h1src : h0src)[(b0 + b) * HH + k]);
      }
      #pragma unroll
      for (int i = 0; i < 25; ++i) {
        const int u  = tid + i * 256;
        const int st = u / 3200, rem = u - st * 3200;
        const int b  = rem / 200, k = rem - b * 200;
        hBh[st][b][k] = (ushort)(tmp[i] & 0xffff);
        hBl[st][b][k] = (ushort)(tmp[i] >> 16);
      }
    }
    if (tid < 128 && xcc7 < 4 && t < TT)
      xc[xb][xcc7] = xtf;
    __syncthreads();

    // ---- MFMA: D[rows x 16 batch] = W * h  (bf16x3) ----
    #pragma unroll
    for (int mt = 0; mt < 2; ++mt) {
      const int T = wave * 2 + mt;
      const bool fc  = isOut && (wave == 2) && (mt == 0);
      const bool val = fc || (T < NT);
      if (!val) continue;
      const int st = fc ? 1 : ((T < T0) ? 0 : 1);
      const ushort* Bh = &hBh[st][m15][0];
      const ushort* Bl = &hBl[st][m15][0];
      f32x4 acc = {0.f, 0.f, 0.f, 0.f};
      #pragma unroll
      for (int kt = 0; kt < 7; ++kt) {
        const short8 bh = *(const short8*)&Bh[kt * 32 + q * 8];
        const short8 bl = *(const short8*)&Bl[kt * 32 + q * 8];
        acc = __builtin_amdgcn_mfma_f32_16x16x32_bf16(Ah[mt][kt], bh, acc, 0, 0, 0);
        acc = __builtin_amdgcn_mfma_f32_16x16x32_bf16(Ah[mt][kt], bl, acc, 0, 0, 0);
        acc = __builtin_amdgcn_mfma_f32_16x16x32_bf16(Al[mt][kt], bh, acc, 0, 0, 0);
      }
      if (fc) {
        if (t >= 2) {
          #pragma unroll
          for (int i = 0; i < 4; ++i) {
            const int p = q * 4 + i;
            if (p < 4)
              out[((b0 + m15) * TT + (t - 2)) * 4 + p] = tanh_fast(acc[i] + bfs[p]);
          }
        }
      } else {
        #pragma unroll
        for (int i = 0; i < 4; ++i) {
          const int p = T * 16 + q * 4 + i;
          int r = -1;
          if (p < h0r) r = p;
          else if (p >= T0 * 16 && (p - T0 * 16) < th) r = h0r + (p - T0 * 16);
          if (r >= 0) D[r][m15] = acc[i];
        }
      }
    }
    __syncthreads();

    // ---- gate combine + coalesced stores (R13 remap) ----
    if (tid < gt) {
      const float hv0 = bfu2f(hBh[0][cb][j0 + cj]) + bfu2f(hBl[0][cb][j0 + cj]);
      const float hv1 = bfu2f(hBh[1][cb][j0 + cj]) + bfu2f(hBl[1][cb][j0 + cj]);
      if (t < TT) {                       // h0(t)
        float ir = bi0[cj], iz = bi0[hs + cj], in_ = bi0[2 * hs + cj];
        #pragma unroll
        for (int c = 0; c < 8; ++c) {
          const float xv = xc[cb][c];
          ir  += Wi0t[c][cj] * xv;
          iz  += Wi0t[c][hs + cj] * xv;
          in_ += Wi0t[c][2 * hs + cj] * xv;
        }
        const float hr = D[cj][cb] + bh0[cj];
        const float hz = D[hs + cj][cb] + bh0[hs + cj];
        const float hn = D[2 * hs + cj][cb] + bh0[2 * hs + cj];
        const float r = sigm(ir + hr), z = sigm(iz + hz);
        const float n = tanh_fast(in_ + r * hn);
        uint* p = &h0g[(t & 1) * (128 * HH) + (b0 + cb) * HH + j0 + cj];
        const uint pv = packf((1.0f - z) * n + z * hv0);
        if (fastp) wg_store_u32(p, pv); else llc_store_u32(p, pv);
      }
      if (t >= 1 && t <= TT) {            // h1(t-1)
        const float ir  = D[3 * hs + cj][cb] + bi1[cj];
        const float iz  = D[4 * hs + cj][cb] + bi1[hs + cj];
        const float in_ = D[5 * hs + cj][cb] + bi1[2 * hs + cj];
        const float hr  = D[6 * hs + cj][cb] + bh1[cj];
        const float hz  = D[7 * hs + cj][cb] + bh1[hs + cj];
        const float hn  = D[8 * hs + cj][cb] + bh1[2 * hs + cj];
        const float r = sigm(ir + hr), z = sigm(iz + hz);
        const float n = tanh_fast(in_ + r * hn);
        uint* p = &h1g[((t + 1) & 1) * (128 * HH) + (b0 + cb) * HH + j0 + cj];
        const uint pv = packf((1.0f - z) * n + z * hv1);
        if (fastp) wg_store_u32(p, pv); else llc_store_u32(p, pv);
      }
    }

    // ---- per-group barrier (R13 structure; primitives per path) ----
    // __syncthreads drains all h stores (vmcnt(0) before s_barrier) -- in
    // fast path that retires them at the shared L2 (the coherence point).
    __syncthreads();
    if (tid == 0) {
      uint* fp = &flags[g * 64 + s * 4];
      if (fastp) wg_store_u32(fp, (uint)(t + 1));
      else       llc_store_u32(fp, (uint)(t + 1));
    }
    if (wave == 0) {
      const uint tgt = (uint)(t + 1);
      const uint* fp = &flags[g * 64 + (lane & 15) * 4];
      for (int it = 0; it < 200000; ++it) {   // bounded: fail-visible
        uint v = tgt;
        if (lane < 16) v = fastp ? l2_load_u32(fp) : llc_load_u32(fp);
        if (__all((int)(v >= tgt))) break;
        __builtin_amdgcn_s_sleep(1);
      }
    }
    __syncthreads();
  }
}

extern "C" void kernel_launch(void* const* d_in, const int* in_sizes, int n_in,
                              void* d_out, int out_size, void* d_ws, size_t ws_size,
                              hipStream_t stream) {
  uint* ws = (uint*)d_ws;
  // ws layout (u32): h0g[2][128][200] @0, h1g[2][128][200] @51200,
  // sync @102400: flags(512) + tok(2048) + verd(512) = 3072 u32.
  // Total 421888 B; ws >= 819200 B proven available (R10/R11 ran that size).
  hipMemsetAsync(d_ws, 0, (size_t)(102400 + 3072) * sizeof(uint), stream);
  gru2_mfma<<<128, 256, 0, stream>>>(
      (const float*)d_in[0],
      (const float*)d_in[1], (const float*)d_in[2],
      (const float*)d_in[3], (const float*)d_in[4],
      (const float*)d_in[5], (const float*)d_in[6],
      (const float*)d_in[7], (const float*)d_in[8],
      (const float*)d_in[9], (const float*)d_in[10],
      (float*)d_out, ws, ws + 51200, ws + 102400);
}

// Round 14
// 6926.958 us; speedup vs baseline: 2.5718x; 2.5718x over previous
//
#include <hip/hip_runtime.h>
#include <hip/hip_bf16.h>

// 2-layer GRU decoder, persistent MFMA kernel. B=128, T=1024, H=200.
// 8 batch-groups (16 batch each) x 16 hidden-slice blocks = 128 blocks.
// Weights live in REGISTERS as bf16 hi/lo MFMA A-fragments; per-step GEMM via
// mfma_f32_16x16x32_bf16 x3 (hi*hi + hi*lo + lo*hi) for fp32-grade precision.
// R17 = R13 (2926us, proven) + SPECULATIVE TAGGED STAGING:
//   h crosses blocks as 8-byte {value,low | step-tag,high} words (R10's
//   verified scheme). Staging loads are issued SPECULATIVELY at iteration
//   top, overlapping the R13-verbatim sleepy flag poll (one 16-lane wave);
//   after the poll passes, tags are checked in-register and only stale words
//   (laggard slice, usually none) are quietly re-loaded. Saves one serial
//   LLC round trip per step without R10's all-thread retry storm.
// R16 lesson recorded: cross-XCD sc0 IS coherent but via slow fabric probes
// (17.8ms) -> the LLC system-scope path is already the fast coherent path.
// Ledger: R3 3157 -> R8 2998 (flag barrier) -> R13 2926 (store remap).
// Lessons held: scope no lever (R9); RMWs pipeline (R8); load-side layout
// untouchable (R11); staging RT-bound not issue-bound (R14); poll = one
// sleepy wave/block (R7/R10/R12); no single-block multiplexing (R15).
// Launcher checks ws_size (needs 821248B; 819200 proven R10/R11) and falls
// back to the R13-verbatim kernel otherwise.

#define TT 1024
#define HH 200
#define NB 16
#define HS 13
#define KP 232   // hB row stride in ushorts; 464 B = 29*16 -> b128-aligned

typedef __attribute__((ext_vector_type(8))) short short8;
typedef __attribute__((ext_vector_type(4))) float f32x4;
typedef unsigned long long ull;

__device__ __forceinline__ float sigm(float v) { return 1.0f / (1.0f + __expf(-v)); }
__device__ __forceinline__ float tanh_fast(float v) {
  float e = __expf(-2.0f * v);
  return (1.0f - e) / (1.0f + e);
}
__device__ __forceinline__ uint llc_load_u32(const uint* p) {
  return __hip_atomic_load(p, __ATOMIC_RELAXED, __HIP_MEMORY_SCOPE_SYSTEM);
}
__device__ __forceinline__ void llc_store_u32(uint* p, uint v) {
  __hip_atomic_store(p, v, __ATOMIC_RELAXED, __HIP_MEMORY_SCOPE_SYSTEM);
}
__device__ __forceinline__ ull ld64(const ull* p) {
  return __hip_atomic_load(p, __ATOMIC_RELAXED, __HIP_MEMORY_SCOPE_SYSTEM);
}
__device__ __forceinline__ void st64(ull* p, ull v) {
  __hip_atomic_store(p, v, __ATOMIC_RELAXED, __HIP_MEMORY_SCOPE_SYSTEM);
}
__device__ __forceinline__ float bfu2f(ushort u) {
  return __uint_as_float(((uint)u) << 16);
}
__device__ __forceinline__ ushort f2bfu(float f) {
  __hip_bfloat16 b = __float2bfloat16(f);
  return *(ushort*)&b;
}
__device__ __forceinline__ uint packf(float h) {
  ushort hi = f2bfu(h);
  float  fh = bfu2f(hi);
  ushort lo = f2bfu(h - fh);
  return (uint)hi | ((uint)lo << 16);
}

// ==================== R17: speculative tagged staging =======================
__global__ __launch_bounds__(256, 1) void gru2_spec(
    const float* __restrict__ x,
    const float* __restrict__ Wih0, const float* __restrict__ Whh0,
    const float* __restrict__ bih0, const float* __restrict__ bhh0,
    const float* __restrict__ Wih1, const float* __restrict__ Whh1,
    const float* __restrict__ bih1, const float* __restrict__ bhh1,
    const float* __restrict__ Wfc,  const float* __restrict__ bfc,
    float* __restrict__ out,
    uint* __restrict__ flags, ull* __restrict__ h0t, ull* __restrict__ h1t)
{
  __shared__ __align__(16) ushort hBh[2][NB][KP];
  __shared__ __align__(16) ushort hBl[2][NB][KP];
  __shared__ float D[117][17];
  __shared__ float Wi0t[8][39];
  __shared__ float bi0[39], bh0[39], bi1[39], bh1[39], bfs[4];
  __shared__ float xc[NB][8];

  const int tid  = threadIdx.x;
  const int wave = tid >> 6;
  const int lane = tid & 63;
  const int m15  = lane & 15;
  const int q    = lane >> 4;

  const int g  = blockIdx.x & 7;
  const int s  = blockIdx.x >> 3;
  const int b0 = g * NB;
  const int j0 = s * HS;
  const int hs = (HH - j0 < HS) ? (HH - j0) : HS;
  const int th   = 3 * hs;
  const int h0r  = 6 * hs;
  const int T0   = (h0r + 15) >> 4;
  const int NT   = T0 + ((th + 15) >> 4);
  const bool isOut = (s == 15);

  // ---- one-time: weight A-fragments into registers (hi/lo bf16) ----
  short8 Ah[2][7], Al[2][7];
  #pragma unroll
  for (int mt = 0; mt < 2; ++mt) {
    const int T = wave * 2 + mt;
    const bool fc  = isOut && (wave == 2) && (mt == 0);
    const bool val = fc || (T < NT);
    #pragma unroll
    for (int kt = 0; kt < 7; ++kt) {
      short8 vh = {0,0,0,0,0,0,0,0}, vl = {0,0,0,0,0,0,0,0};
      #pragma unroll
      for (int j = 0; j < 8; ++j) {
        const int k = kt * 32 + q * 8 + j;
        float w = 0.0f;
        if (val && k < HH) {
          if (fc) {
            if (m15 < 4) w = Wfc[m15 * HH + k];
          } else {
            const int p = T * 16 + m15;
            int r = -1;
            if (p < h0r) r = p;
            else if (p >= T0 * 16 && (p - T0 * 16) < th) r = h0r + (p - T0 * 16);
            if (r >= 0) {
              const int m  = r / th, rr = r - m * th;
              const int qq = rr / hs, jj = rr - qq * hs;
              const float* src = (m == 0) ? Whh0 : ((m == 1) ? Wih1 : Whh1);
              w = src[(qq * HH + j0 + jj) * HH + k];
            }
          }
        }
        const ushort uh = f2bfu(w);
        const ushort ul = f2bfu(w - bfu2f(uh));
        vh[j] = (short)uh; vl[j] = (short)ul;
      }
      Ah[mt][kt] = vh; Al[mt][kt] = vl;
    }
  }

  // ---- one-time: small LDS tables ----
  for (int u = tid; u < th * 8; u += 256) {
    int rr = u >> 3, c = u & 7;
    int qq = rr / hs, jj = rr - qq * hs;
    Wi0t[c][rr] = Wih0[(qq * HH + j0 + jj) * 8 + c];
  }
  for (int u = tid; u < th; u += 256) {
    int qq = u / hs, jj = u - qq * hs;
    int grow = qq * HH + j0 + jj;
    bi0[u] = bih0[grow]; bh0[u] = bhh0[grow];
    bi1[u] = bih1[grow]; bh1[u] = bhh1[grow];
  }
  if (tid < 4) bfs[tid] = bfc[tid];
  for (int u = tid; u < 2 * NB * KP / 2; u += 256) ((uint*)hBh)[u] = 0;
  for (int u = tid; u < 2 * NB * KP / 2; u += 256) ((uint*)hBl)[u] = 0;
  if (tid < 128 && (tid & 7) >= 4)   // emotion columns: t-invariant
    xc[tid >> 3][tid & 7] = x[(b0 + (tid >> 3)) * TT * 8 + (tid & 7)];
  __syncthreads();

  // ---- per-thread staging constants (R10-verified decomposition) ----
  // word i covers u = tid + i*256, u in [0,6400): st=u/3200, b=(u%3200)/200,
  // k=u%200; element index (b0+b)*HH + k.
  int su[25]; uint stmask = 0;
  #pragma unroll
  for (int i = 0; i < 25; ++i) {
    const int u = tid + i * 256;
    const int st = u / 3200, rem = u - st * 3200;
    const int b = rem / 200, k = rem - b * 200;
    su[i] = (b0 + b) * HH + k;
    stmask |= (uint)st << i;
  }

  // Gate-combine remap (R13, proven): cb = tid/hs, cj = tid%hs.
  const int gt = 16 * hs;
  const int cb = tid / hs;
  const int cj = tid - cb * hs;
  const int xb = tid >> 3, xcc7 = tid & 7;

  for (int t = 0; t <= TT + 1; ++t) {
    // ---- hoist teacher-forcing x load ----
    float xtf = 1.0f;
    if (tid < 128 && xcc7 < 4 && t > 0 && t < TT)
      xtf = x[((b0 + xb) * TT + (t - 1)) * 8 + xcc7];

    // ---- SPECULATIVE staging issue (overlaps the flag poll below) ----
    const int s0 = ((t + 1) & 1) * 25600;   // h0(t-1) slot base (ull elems)
    const int s1 = (t & 1) * 25600;         // h1(t-2) slot base
    ull w[25];
    #pragma unroll
    for (int i = 0; i < 25; ++i)
      w[i] = ld64((((stmask >> i) & 1) ? h1t + s1 : h0t + s0) + su[i]);

    // ---- R13-verbatim sleepy poll (one wave), concurrent with loads ----
    if (wave == 0 && t > 0) {
      const uint tgt = (uint)t;
      const uint* fp = &flags[g * 64 + (lane & 15) * 4];
      for (int it = 0; it < 200000; ++it) {   // bounded: fail-visible
        uint v = tgt;
        if (lane < 16) v = llc_load_u32(fp);
        if (__all((int)(v >= tgt))) break;
        __builtin_amdgcn_s_sleep(1);
      }
    }
    __syncthreads();   // B1: poll passed AND speculative loads returned

    // ---- tag check + quiet re-load of stale words (post-poll: fresh) ----
    {
      const uint etag0 = (uint)t;
      const uint etag1 = (t >= 2) ? (uint)t : 0u;
      const bool chk0  = (t <= TT);
      uint pend = 0;
      #pragma unroll
      for (int i = 0; i < 25; ++i) {
        const bool is1 = (stmask >> i) & 1;
        const uint et  = is1 ? etag1 : etag0;
        if ((is1 || chk0) && (uint)(w[i] >> 32) != et) pend |= 1u << i;
      }
      for (int it = 0; it < 5000 && pend; ++it) {
        uint np = 0;
        #pragma unroll
        for (int i = 0; i < 25; ++i) {
          if (pend & (1u << i)) {
            const bool is1 = (stmask >> i) & 1;
            w[i] = ld64((is1 ? h1t + s1 : h0t + s0) + su[i]);
            const uint et = is1 ? etag1 : etag0;
            if ((uint)(w[i] >> 32) != et) np |= 1u << i;
          }
        }
        pend = np;
        if (np) __builtin_amdgcn_s_sleep(1);
      }
    }

    // ---- unpack values into LDS bf16 hi/lo planes ----
    #pragma unroll
    for (int i = 0; i < 25; ++i) {
      const int u = tid + i * 256;
      const int st = u / 3200, rem = u - st * 3200;
      const int b = rem / 200, k = rem - b * 200;
      const uint v = (uint)w[i];
      hBh[st][b][k] = (ushort)(v & 0xffff);
      hBl[st][b][k] = (ushort)(v >> 16);
    }
    if (tid < 128 && xcc7 < 4 && t < TT)
      xc[xb][xcc7] = xtf;
    __syncthreads();   // B2: LDS ready

    // ---- MFMA: D[rows x 16 batch] = W * h  (bf16x3) ----
    #pragma unroll
    for (int mt = 0; mt < 2; ++mt) {
      const int T = wave * 2 + mt;
      const bool fc  = isOut && (wave == 2) && (mt == 0);
      const bool val = fc || (T < NT);
      if (!val) continue;
      const int st = fc ? 1 : ((T < T0) ? 0 : 1);
      const ushort* Bh = &hBh[st][m15][0];
      const ushort* Bl = &hBl[st][m15][0];
      f32x4 acc = {0.f, 0.f, 0.f, 0.f};
      #pragma unroll
      for (int kt = 0; kt < 7; ++kt) {
        const short8 bh = *(const short8*)&Bh[kt * 32 + q * 8];
        const short8 bl = *(const short8*)&Bl[kt * 32 + q * 8];
        acc = __builtin_amdgcn_mfma_f32_16x16x32_bf16(Ah[mt][kt], bh, acc, 0, 0, 0);
        acc = __builtin_amdgcn_mfma_f32_16x16x32_bf16(Ah[mt][kt], bl, acc, 0, 0, 0);
        acc = __builtin_amdgcn_mfma_f32_16x16x32_bf16(Al[mt][kt], bh, acc, 0, 0, 0);
      }
      if (fc) {                              // FC head: out(t-2)
        if (t >= 2) {
          #pragma unroll
          for (int i = 0; i < 4; ++i) {
            const int p = q * 4 + i;
            if (p < 4)
              out[((b0 + m15) * TT + (t - 2)) * 4 + p] = tanh_fast(acc[i] + bfs[p]);
          }
        }
      } else {
        #pragma unroll
        for (int i = 0; i < 4; ++i) {
          const int p = T * 16 + q * 4 + i;
          int r = -1;
          if (p < h0r) r = p;
          else if (p >= T0 * 16 && (p - T0 * 16) < th) r = h0r + (p - T0 * 16);
          if (r >= 0) D[r][m15] = acc[i];
        }
      }
    }
    __syncthreads();   // B3: D ready

    // ---- gate combine + coalesced TAGGED stores (tag = t+1) ----
    if (tid < gt) {
      const float hv0 = bfu2f(hBh[0][cb][j0 + cj]) + bfu2f(hBl[0][cb][j0 + cj]);
      const float hv1 = bfu2f(hBh[1][cb][j0 + cj]) + bfu2f(hBl[1][cb][j0 + cj]);
      const ull tag = ((ull)(uint)(t + 1)) << 32;
      if (t < TT) {                       // h0(t)
        float ir = bi0[cj], iz = bi0[hs + cj], in_ = bi0[2 * hs + cj];
        #pragma unroll
        for (int c = 0; c < 8; ++c) {
          const float xv = xc[cb][c];
          ir  += Wi0t[c][cj] * xv;
          iz  += Wi0t[c][hs + cj] * xv;
          in_ += Wi0t[c][2 * hs + cj] * xv;
        }
        const float hr = D[cj][cb] + bh0[cj];
        const float hz = D[hs + cj][cb] + bh0[hs + cj];
        const float hn = D[2 * hs + cj][cb] + bh0[2 * hs + cj];
        const float r = sigm(ir + hr), z = sigm(iz + hz);
        const float n = tanh_fast(in_ + r * hn);
        st64(&h0t[(t & 1) * 25600 + (b0 + cb) * HH + j0 + cj],
             (ull)packf((1.0f - z) * n + z * hv0) | tag);
      }
      if (t >= 1 && t <= TT) {            // h1(t-1)
        const float ir  = D[3 * hs + cj][cb] + bi1[cj];
        const float iz  = D[4 * hs + cj][cb] + bi1[hs + cj];
        const float in_ = D[5 * hs + cj][cb] + bi1[2 * hs + cj];
        const float hr  = D[6 * hs + cj][cb] + bh1[cj];
        const float hz  = D[7 * hs + cj][cb] + bh1[hs + cj];
        const float hn  = D[8 * hs + cj][cb] + bh1[2 * hs + cj];
        const float r = sigm(ir + hr), z = sigm(iz + hz);
        const float n = tanh_fast(in_ + r * hn);
        st64(&h1t[((t + 1) & 1) * 25600 + (b0 + cb) * HH + j0 + cj],
             (ull)packf((1.0f - z) * n + z * hv1) | tag);
      }
    }

    __syncthreads();   // B4: drains gate stores (vmcnt0 before s_barrier)
    if (tid == 0)
      llc_store_u32(&flags[g * 64 + s * 4], (uint)(t + 1));
  }
}

// ==================== fallback: R13-verbatim (proven, 2926us) ===============
__global__ __launch_bounds__(256, 1) void gru2_r13(
    const float* __restrict__ x,
    const float* __restrict__ Wih0, const float* __restrict__ Whh0,
    const float* __restrict__ bih0, const float* __restrict__ bhh0,
    const float* __restrict__ Wih1, const float* __restrict__ Whh1,
    const float* __restrict__ bih1, const float* __restrict__ bhh1,
    const float* __restrict__ Wfc,  const float* __restrict__ bfc,
    float* __restrict__ out,
    uint* __restrict__ h0g, uint* __restrict__ h1g, uint* __restrict__ syncp)
{
  __shared__ __align__(16) ushort hBh[2][NB][KP];
  __shared__ __align__(16) ushort hBl[2][NB][KP];
  __shared__ float D[117][17];
  __shared__ float Wi0t[8][39];
  __shared__ float bi0[39], bh0[39], bi1[39], bh1[39], bfs[4];
  __shared__ float xc[NB][8];

  const int tid  = threadIdx.x;
  const int wave = tid >> 6;
  const int lane = tid & 63;
  const int m15  = lane & 15;
  const int q    = lane >> 4;

  const int g  = blockIdx.x & 7;
  const int s  = blockIdx.x >> 3;
  const int b0 = g * NB;
  const int j0 = s * HS;
  const int hs = (HH - j0 < HS) ? (HH - j0) : HS;
  const int th   = 3 * hs;
  const int h0r  = 6 * hs;
  const int T0   = (h0r + 15) >> 4;
  const int NT   = T0 + ((th + 15) >> 4);
  const bool isOut = (s == 15);

  uint* flags = syncp;

  short8 Ah[2][7], Al[2][7];
  #pragma unroll
  for (int mt = 0; mt < 2; ++mt) {
    const int T = wave * 2 + mt;
    const bool fc  = isOut && (wave == 2) && (mt == 0);
    const bool val = fc || (T < NT);
    #pragma unroll
    for (int kt = 0; kt < 7; ++kt) {
      short8 vh = {0,0,0,0,0,0,0,0}, vl = {0,0,0,0,0,0,0,0};
      #pragma unroll
      for (int j = 0; j < 8; ++j) {
        const int k = kt * 32 + q * 8 + j;
        float w = 0.0f;
        if (val && k < HH) {
          if (fc) {
            if (m15 < 4) w = Wfc[m15 * HH + k];
          } else {
            const int p = T * 16 + m15;
            int r = -1;
            if (p < h0r) r = p;
            else if (p >= T0 * 16 && (p - T0 * 16) < th) r = h0r + (p - T0 * 16);
            if (r >= 0) {
              const int m  = r / th, rr = r - m * th;
              const int qq = rr / hs, jj = rr - qq * hs;
              const float* src = (m == 0) ? Whh0 : ((m == 1) ? Wih1 : Whh1);
              w = src[(qq * HH + j0 + jj) * HH + k];
            }
          }
        }
        const ushort uh = f2bfu(w);
        const ushort ul = f2bfu(w - bfu2f(uh));
        vh[j] = (short)uh; vl[j] = (short)ul;
      }
      Ah[mt][kt] = vh; Al[mt][kt] = vl;
    }
  }

  for (int u = tid; u < th * 8; u += 256) {
    int rr = u >> 3, c = u & 7;
    int qq = rr / hs, jj = rr - qq * hs;
    Wi0t[c][rr] = Wih0[(qq * HH + j0 + jj) * 8 + c];
  }
  for (int u = tid; u < th; u += 256) {
    int qq = u / hs, jj = u - qq * hs;
    int grow = qq * HH + j0 + jj;
    bi0[u] = bih0[grow]; bh0[u] = bhh0[grow];
    bi1[u] = bih1[grow]; bh1[u] = bhh1[grow];
  }
  if (tid < 4) bfs[tid] = bfc[tid];
  for (int u = tid; u < 2 * NB * KP / 2; u += 256) ((uint*)hBh)[u] = 0;
  for (int u = tid; u < 2 * NB * KP / 2; u += 256) ((uint*)hBl)[u] = 0;
  if (tid < 128 && (tid & 7) >= 4)
    xc[tid >> 3][tid & 7] = x[(b0 + (tid >> 3)) * TT * 8 + (tid & 7)];
  __syncthreads();

  const int gt = 16 * hs;
  const int cb = tid / hs;
  const int cj = tid - cb * hs;
  const int xb = tid >> 3, xcc7 = tid & 7;

  for (int t = 0; t <= TT + 1; ++t) {
    float xtf = 1.0f;
    if (tid < 128 && xcc7 < 4 && t > 0 && t < TT)
      xtf = x[((b0 + xb) * TT + (t - 1)) * 8 + xcc7];

    const uint* h0src = h0g + ((t + 1) & 1) * (128 * HH);
    const uint* h1src = h1g + (t & 1) * (128 * HH);
    uint tmp[25];
    #pragma unroll
    for (int i = 0; i < 25; ++i) {
      const int u  = tid + i * 256;
      const int st = u / 3200, rem = u - st * 3200;
      const int b  = rem / 200, k = rem - b * 200;
      tmp[i] = llc_load_u32(&(st ? h1src : h0src)[(b0 + b) * HH + k]);
    }
    #pragma unroll
    for (int i = 0; i < 25; ++i) {
      const int u  = tid + i * 256;
      const int st = u / 3200, rem = u - st * 3200;
      const int b  = rem / 200, k = rem - b * 200;
      hBh[st][b][k] = (ushort)(tmp[i] & 0xffff);
      hBl[st][b][k] = (ushort)(tmp[i] >> 16);
    }
    if (tid < 128 && xcc7 < 4 && t < TT)
      xc[xb][xcc7] = xtf;
    __syncthreads();

    #pragma unroll
    for (int mt = 0; mt < 2; ++mt) {
      const int T = wave * 2 + mt;
      const bool fc  = isOut && (wave == 2) && (mt == 0);
      const bool val = fc || (T < NT);
      if (!val) continue;
      const int st = fc ? 1 : ((T < T0) ? 0 : 1);
      const ushort* Bh = &hBh[st][m15][0];
      const ushort* Bl = &hBl[st][m15][0];
      f32x4 acc = {0.f, 0.f, 0.f, 0.f};
      #pragma unroll
      for (int kt = 0; kt < 7; ++kt) {
        const short8 bh = *(const short8*)&Bh[kt * 32 + q * 8];
        const short8 bl = *(const short8*)&Bl[kt * 32 + q * 8];
        acc = __builtin_amdgcn_mfma_f32_16x16x32_bf16(Ah[mt][kt], bh, acc, 0, 0, 0);
        acc = __builtin_amdgcn_mfma_f32_16x16x32_bf16(Ah[mt][kt], bl, acc, 0, 0, 0);
        acc = __builtin_amdgcn_mfma_f32_16x16x32_bf16(Al[mt][kt], bh, acc, 0, 0, 0);
      }
      if (fc) {
        if (t >= 2) {
          #pragma unroll
          for (int i = 0; i < 4; ++i) {
            const int p = q * 4 + i;
            if (p < 4)
              out[((b0 + m15) * TT + (t - 2)) * 4 + p] = tanh_fast(acc[i] + bfs[p]);
          }
        }
      } else {
        #pragma unroll
        for (int i = 0; i < 4; ++i) {
          const int p = T * 16 + q * 4 + i;
          int r = -1;
          if (p < h0r) r = p;
          else if (p >= T0 * 16 && (p - T0 * 16) < th) r = h0r + (p - T0 * 16);
          if (r >= 0) D[r][m15] = acc[i];
        }
      }
    }
    __syncthreads();

    if (tid < gt) {
      const float hv0 = bfu2f(hBh[0][cb][j0 + cj]) + bfu2f(hBl[0][cb][j0 + cj]);
      const float hv1 = bfu2f(hBh[1][cb][j0 + cj]) + bfu2f(hBl[1][cb][j0 + cj]);
      if (t < TT) {
        float ir = bi0[cj], iz = bi0[hs + cj], in_ = bi0[2 * hs + cj];
        #pragma unroll
        for (int c = 0; c < 8; ++c) {
          const float xv = xc[cb][c];
          ir  += Wi0t[c][cj] * xv;
          iz  += Wi0t[c][hs + cj] * xv;
          in_ += Wi0t[c][2 * hs + cj] * xv;
        }
        const float hr = D[cj][cb] + bh0[cj];
        const float hz = D[hs + cj][cb] + bh0[hs + cj];
        const float hn = D[2 * hs + cj][cb] + bh0[2 * hs + cj];
        const float r = sigm(ir + hr), z = sigm(iz + hz);
        const float n = tanh_fast(in_ + r * hn);
        llc_store_u32(&h0g[(t & 1) * (128 * HH) + (b0 + cb) * HH + j0 + cj],
                      packf((1.0f - z) * n + z * hv0));
      }
      if (t >= 1 && t <= TT) {
        const float ir  = D[3 * hs + cj][cb] + bi1[cj];
        const float iz  = D[4 * hs + cj][cb] + bi1[hs + cj];
        const float in_ = D[5 * hs + cj][cb] + bi1[2 * hs + cj];
        const float hr  = D[6 * hs + cj][cb] + bh1[cj];
        const float hz  = D[7 * hs + cj][cb] + bh1[hs + cj];
        const float hn  = D[8 * hs + cj][cb] + bh1[2 * hs + cj];
        const float r = sigm(ir + hr), z = sigm(iz + hz);
        const float n = tanh_fast(in_ + r * hn);
        llc_store_u32(&h1g[((t + 1) & 1) * (128 * HH) + (b0 + cb) * HH + j0 + cj],
                      packf((1.0f - z) * n + z * hv1));
      }
    }

    __syncthreads();
    if (tid == 0)
      llc_store_u32(&flags[g * 64 + s * 4], (uint)(t + 1));
    if (wave == 0) {
      const uint tgt = (uint)(t + 1);
      const uint* fp = &flags[g * 64 + (lane & 15) * 4];
      for (int it = 0; it < 200000; ++it) {
        uint v = tgt;
        if (lane < 16) v = llc_load_u32(fp);
        if (__all((int)(v >= tgt))) break;
        __builtin_amdgcn_s_sleep(1);
      }
    }
    __syncthreads();
  }
}

extern "C" void kernel_launch(void* const* d_in, const int* in_sizes, int n_in,
                              void* d_out, int out_size, void* d_ws, size_t ws_size,
                              hipStream_t stream) {
  uint* ws = (uint*)d_ws;
  // R17 layout (u32 units): flags 512 @0, h0t (51200 ull) @512,
  // h1t (51200 ull) @102912. Total (512 + 204800)*4 = 821248 B.
  const size_t need = (size_t)(512 + 204800) * sizeof(uint);
  if (ws_size >= need) {
    hipMemsetAsync(d_ws, 0, need, stream);
    gru2_spec<<<128, 256, 0, stream>>>(
        (const float*)d_in[0],
        (const float*)d_in[1], (const float*)d_in[2],
        (const float*)d_in[3], (const float*)d_in[4],
        (const float*)d_in[5], (const float*)d_in[6],
        (const float*)d_in[7], (const float*)d_in[8],
        (const float*)d_in[9], (const float*)d_in[10],
        (float*)d_out, ws, (ull*)(ws + 512), (ull*)(ws + 512) + 51200);
  } else {
    // R13-verbatim fallback: h0g @0, h1g @51200, flags @102400 (u32).
    hipMemsetAsync(d_ws, 0, (size_t)(102400 + 512) * sizeof(uint), stream);
    gru2_r13<<<128, 256, 0, stream>>>(
        (const float*)d_in[0],
        (const float*)d_in[1], (const float*)d_in[2],
        (const float*)d_in[3], (const float*)d_in[4],
        (const float*)d_in[5], (const float*)d_in[6],
        (const float*)d_in[7], (const float*)d_in[8],
        (const float*)d_in[9], (const float*)d_in[10],
        (float*)d_out, ws, ws + 51200, ws + 102400);
  }
}

// Round 15
// 3263.121 us; speedup vs baseline: 5.4594x; 2.1228x over previous
//
#include <hip/hip_runtime.h>
#include <hip/hip_bf16.h>

// 2-layer GRU decoder, persistent MFMA kernel. B=128, T=1024, H=200.
// 8 batch-groups (16 batch each) x 16 hidden-slice blocks = 128 blocks.
// Weights live in REGISTERS as bf16 hi/lo MFMA A-fragments; per-step GEMM via
// mfma_f32_16x16x32_bf16 x3 (hi*hi + hi*lo + lo*hi) for fp32-grade precision.
// R18 = R13 (2926us, proven) + EXACTLY ONE change: POLL PREFETCH ACROSS THE
// DRAIN BARRIER. Wave 0 issues peer-flag loads for t+1 BEFORE the pre-flag
// __syncthreads; the sync's vmcnt(0) drain (paid anyway for h stores) also
// retires those loads, so right after the flag store wave 0 already holds
// flag values -- common case passes with ZERO additional detect round trip.
// Laggard case: R13 poll, first 3 rounds eager (no s_sleep; 128 pollers x
// 4 lines << R7's storm threshold), then sleepy bounded.
// R17 lesson recorded: speculation BEFORE the producer store window is pure
// waste (always stale, 3x FETCH, invalidation pressure). Prefetching the
// FLAG across the drain is different: it samples at the moment peers are
// expected to have flagged.
// Ledger: R3 3157 -> R8 2998 (flag barrier) -> R13 2926 (store remap).
// Lessons held: scope no lever (R9); RMWs pipeline (R8); load-side layout
// untouchable (R11); staging RT-bound not issue-bound (R14); poll = one
// sleepy wave/block (R7/R10/R12); no multiplexing (R15); L2 exchange dead
// (R16: cross-XCD sc0 coherent but via slow fabric probes); no speculative
// data loads (R17).

#define TT 1024
#define HH 200
#define NB 16
#define HS 13
#define KP 232   // hB row stride in ushorts; 464 B = 29*16 -> b128-aligned

typedef __attribute__((ext_vector_type(8))) short short8;
typedef __attribute__((ext_vector_type(4))) float f32x4;

__device__ __forceinline__ float sigm(float v) { return 1.0f / (1.0f + __expf(-v)); }
__device__ __forceinline__ float tanh_fast(float v) {
  float e = __expf(-2.0f * v);
  return (1.0f - e) / (1.0f + e);
}
__device__ __forceinline__ uint llc_load_u32(const uint* p) {
  return __hip_atomic_load(p, __ATOMIC_RELAXED, __HIP_MEMORY_SCOPE_SYSTEM);
}
__device__ __forceinline__ void llc_store_u32(uint* p, uint v) {
  __hip_atomic_store(p, v, __ATOMIC_RELAXED, __HIP_MEMORY_SCOPE_SYSTEM);
}
__device__ __forceinline__ float bfu2f(ushort u) {
  return __uint_as_float(((uint)u) << 16);
}
__device__ __forceinline__ ushort f2bfu(float f) {
  __hip_bfloat16 b = __float2bfloat16(f);
  return *(ushort*)&b;
}
__device__ __forceinline__ uint packf(float h) {
  ushort hi = f2bfu(h);
  float  fh = bfu2f(hi);
  ushort lo = f2bfu(h - fh);
  return (uint)hi | ((uint)lo << 16);
}

__global__ __launch_bounds__(256, 1) void gru2_mfma(
    const float* __restrict__ x,
    const float* __restrict__ Wih0, const float* __restrict__ Whh0,
    const float* __restrict__ bih0, const float* __restrict__ bhh0,
    const float* __restrict__ Wih1, const float* __restrict__ Whh1,
    const float* __restrict__ bih1, const float* __restrict__ bhh1,
    const float* __restrict__ Wfc,  const float* __restrict__ bfc,
    float* __restrict__ out,
    uint* __restrict__ h0g, uint* __restrict__ h1g, uint* __restrict__ syncp)
{
  // LDS: bf16 hi/lo planes of h0,h1 (B-operand layout), D results, misc.
  __shared__ __align__(16) ushort hBh[2][NB][KP];
  __shared__ __align__(16) ushort hBl[2][NB][KP];
  __shared__ float D[117][17];
  __shared__ float Wi0t[8][39];     // transposed: clean reads under remap
  __shared__ float bi0[39], bh0[39], bi1[39], bh1[39], bfs[4];
  __shared__ float xc[NB][8];

  const int tid  = threadIdx.x;
  const int wave = tid >> 6;
  const int lane = tid & 63;
  const int m15  = lane & 15;   // MFMA row (A) / col (B,C)
  const int q    = lane >> 4;   // MFMA quad

  const int g  = blockIdx.x & 7;    // batch-group
  const int s  = blockIdx.x >> 3;   // hidden-slice
  const int b0 = g * NB;
  const int j0 = s * HS;
  const int hs = (HH - j0 < HS) ? (HH - j0) : HS;   // 13 (s<15) or 5 (s==15)
  const int th   = 3 * hs;
  const int h0r  = 6 * hs;                          // rows dotted with h0
  const int T0   = (h0r + 15) >> 4;                 // 5 or 2  (h0 tiles)
  const int NT   = T0 + ((th + 15) >> 4);           // 8 or 3  (total tiles)
  const bool isOut = (s == 15);

  // sync region (512 u32, footprint identical to proven R3/R8/R13):
  // flag(g,s) at syncp[g*64 + s*4] -- 16B spacing, R8-verbatim.
  uint* flags = syncp;

  // ---- one-time: weight A-fragments into registers (hi/lo bf16) ----
  short8 Ah[2][7], Al[2][7];
  #pragma unroll
  for (int mt = 0; mt < 2; ++mt) {
    const int T = wave * 2 + mt;
    const bool fc  = isOut && (wave == 2) && (mt == 0);
    const bool val = fc || (T < NT);
    #pragma unroll
    for (int kt = 0; kt < 7; ++kt) {
      short8 vh = {0,0,0,0,0,0,0,0}, vl = {0,0,0,0,0,0,0,0};
      #pragma unroll
      for (int j = 0; j < 8; ++j) {
        const int k = kt * 32 + q * 8 + j;
        float w = 0.0f;
        if (val && k < HH) {
          if (fc) {
            if (m15 < 4) w = Wfc[m15 * HH + k];
          } else {
            const int p = T * 16 + m15;
            int r = -1;
            if (p < h0r) r = p;
            else if (p >= T0 * 16 && (p - T0 * 16) < th) r = h0r + (p - T0 * 16);
            if (r >= 0) {
              const int m  = r / th, rr = r - m * th;
              const int qq = rr / hs, jj = rr - qq * hs;
              const float* src = (m == 0) ? Whh0 : ((m == 1) ? Wih1 : Whh1);
              w = src[(qq * HH + j0 + jj) * HH + k];
            }
          }
        }
        const ushort uh = f2bfu(w);
        const ushort ul = f2bfu(w - bfu2f(uh));
        vh[j] = (short)uh; vl[j] = (short)ul;
      }
      Ah[mt][kt] = vh; Al[mt][kt] = vl;
    }
  }

  // ---- one-time: small LDS tables ----
  for (int u = tid; u < th * 8; u += 256) {
    int rr = u >> 3, c = u & 7;
    int qq = rr / hs, jj = rr - qq * hs;
    Wi0t[c][rr] = Wih0[(qq * HH + j0 + jj) * 8 + c];
  }
  for (int u = tid; u < th; u += 256) {
    int qq = u / hs, jj = u - qq * hs;
    int grow = qq * HH + j0 + jj;
    bi0[u] = bih0[grow]; bh0[u] = bhh0[grow];
    bi1[u] = bih1[grow]; bh1[u] = bhh1[grow];
  }
  if (tid < 4) bfs[tid] = bfc[tid];
  for (int u = tid; u < 2 * NB * KP / 2; u += 256) ((uint*)hBh)[u] = 0;  // zero pads
  for (int u = tid; u < 2 * NB * KP / 2; u += 256) ((uint*)hBl)[u] = 0;
  // Emotion columns of xc are t-invariant: write once.
  if (tid < 128 && (tid & 7) >= 4)
    xc[tid >> 3][tid & 7] = x[(b0 + (tid >> 3)) * TT * 8 + (tid & 7)];
  __syncthreads();

  // Gate-combine remap (R13, proven): cb = tid/hs, cj = tid%hs.
  const int gt = 16 * hs;
  const int cb = tid / hs;
  const int cj = tid - cb * hs;
  const int xb = tid >> 3, xcc7 = tid & 7;  // xc staging indices
  const uint* myfp = &flags[g * 64 + (lane & 15) * 4];

  for (int t = 0; t <= TT + 1; ++t) {
    // ---- hoist teacher-forcing x load (overlaps staging round trip) ----
    float xtf = 1.0f;
    if (tid < 128 && xcc7 < 4 && t > 0 && t < TT)
      xtf = x[((b0 + xb) * TT + (t - 1)) * 8 + xcc7];

    // ---- stage h0(t-1), h1(t-2): byte-identical to R13 (proven) ----
    const uint* h0src = h0g + ((t + 1) & 1) * (128 * HH);
    const uint* h1src = h1g + (t & 1) * (128 * HH);
    uint tmp[25];                          // 2 states x 16 b x 200 k = 6400
    #pragma unroll
    for (int i = 0; i < 25; ++i) {
      const int u  = tid + i * 256;
      const int st = u / 3200, rem = u - st * 3200;
      const int b  = rem / 200, k = rem - b * 200;
      tmp[i] = llc_load_u32(&(st ? h1src : h0src)[(b0 + b) * HH + k]);
    }
    #pragma unroll
    for (int i = 0; i < 25; ++i) {
      const int u  = tid + i * 256;
      const int st = u / 3200, rem = u - st * 3200;
      const int b  = rem / 200, k = rem - b * 200;
      hBh[st][b][k] = (ushort)(tmp[i] & 0xffff);
      hBl[st][b][k] = (ushort)(tmp[i] >> 16);
    }
    if (tid < 128 && xcc7 < 4 && t < TT)   // tf columns (t==0 -> 1.0f)
      xc[xb][xcc7] = xtf;
    __syncthreads();

    // ---- MFMA: D[rows x 16 batch] = W * h  (bf16x3) ----
    #pragma unroll
    for (int mt = 0; mt < 2; ++mt) {
      const int T = wave * 2 + mt;
      const bool fc  = isOut && (wave == 2) && (mt == 0);
      const bool val = fc || (T < NT);
      if (!val) continue;
      const int st = fc ? 1 : ((T < T0) ? 0 : 1);
      const ushort* Bh = &hBh[st][m15][0];
      const ushort* Bl = &hBl[st][m15][0];
      f32x4 acc = {0.f, 0.f, 0.f, 0.f};
      #pragma unroll
      for (int kt = 0; kt < 7; ++kt) {
        const short8 bh = *(const short8*)&Bh[kt * 32 + q * 8];
        const short8 bl = *(const short8*)&Bl[kt * 32 + q * 8];
        acc = __builtin_amdgcn_mfma_f32_16x16x32_bf16(Ah[mt][kt], bh, acc, 0, 0, 0);
        acc = __builtin_amdgcn_mfma_f32_16x16x32_bf16(Ah[mt][kt], bl, acc, 0, 0, 0);
        acc = __builtin_amdgcn_mfma_f32_16x16x32_bf16(Al[mt][kt], bh, acc, 0, 0, 0);
      }
      if (fc) {                              // FC head: out(t-2)
        if (t >= 2) {
          #pragma unroll
          for (int i = 0; i < 4; ++i) {
            const int p = q * 4 + i;
            if (p < 4)
              out[((b0 + m15) * TT + (t - 2)) * 4 + p] = tanh_fast(acc[i] + bfs[p]);
          }
        }
      } else {
        #pragma unroll
        for (int i = 0; i < 4; ++i) {
          const int p = T * 16 + q * 4 + i;
          int r = -1;
          if (p < h0r) r = p;
          else if (p >= T0 * 16 && (p - T0 * 16) < th) r = h0r + (p - T0 * 16);
          if (r >= 0) D[r][m15] = acc[i];
        }
      }
    }
    __syncthreads();

    // ---- gate combine + coalesced stores (R13-verbatim) ----
    if (tid < gt) {
      const float hv0 = bfu2f(hBh[0][cb][j0 + cj]) + bfu2f(hBl[0][cb][j0 + cj]);
      const float hv1 = bfu2f(hBh[1][cb][j0 + cj]) + bfu2f(hBl[1][cb][j0 + cj]);
      if (t < TT) {                       // h0(t)
        float ir = bi0[cj], iz = bi0[hs + cj], in_ = bi0[2 * hs + cj];
        #pragma unroll
        for (int c = 0; c < 8; ++c) {
          const float xv = xc[cb][c];
          ir  += Wi0t[c][cj] * xv;
          iz  += Wi0t[c][hs + cj] * xv;
          in_ += Wi0t[c][2 * hs + cj] * xv;
        }
        const float hr = D[cj][cb] + bh0[cj];
        const float hz = D[hs + cj][cb] + bh0[hs + cj];
        const float hn = D[2 * hs + cj][cb] + bh0[2 * hs + cj];
        const float r = sigm(ir + hr), z = sigm(iz + hz);
        const float n = tanh_fast(in_ + r * hn);
        llc_store_u32(&h0g[(t & 1) * (128 * HH) + (b0 + cb) * HH + j0 + cj],
                      packf((1.0f - z) * n + z * hv0));
      }
      if (t >= 1 && t <= TT) {            // h1(t-1)
        const float ir  = D[3 * hs + cj][cb] + bi1[cj];
        const float iz  = D[4 * hs + cj][cb] + bi1[hs + cj];
        const float in_ = D[5 * hs + cj][cb] + bi1[2 * hs + cj];
        const float hr  = D[6 * hs + cj][cb] + bh1[cj];
        const float hz  = D[7 * hs + cj][cb] + bh1[hs + cj];
        const float hn  = D[8 * hs + cj][cb] + bh1[2 * hs + cj];
        const float r = sigm(ir + hr), z = sigm(iz + hz);
        const float n = tanh_fast(in_ + r * hn);
        llc_store_u32(&h1g[((t + 1) & 1) * (128 * HH) + (b0 + cb) * HH + j0 + cj],
                      packf((1.0f - z) * n + z * hv1));
      }
    }

    // ---- per-group barrier: prefetched poll (THE change vs R13) ----
    // Wave 0 issues the peer-flag loads for t+1 BEFORE the drain sync; the
    // sync's vmcnt(0) retires them, so the post-flag check starts with flag
    // values already in registers (common case: pass with 0 extra RT).
    const uint tgt = (uint)(t + 1);
    uint pv = tgt;
    if (wave == 0 && lane < 16)
      pv = llc_load_u32(myfp);             // prefetch (may be stale)
    __syncthreads();                       // drains h stores + prefetch loads
    if (tid == 0)
      llc_store_u32(&flags[g * 64 + s * 4], tgt);
    if (wave == 0) {
      if (!__all((int)(pv >= tgt))) {
        // Laggards: 3 eager rounds (no sleep), then sleepy bounded (R13).
        for (int it = 0; it < 200000; ++it) {
          uint v = tgt;
          if (lane < 16) v = llc_load_u32(myfp);
          if (__all((int)(v >= tgt))) break;
          if (it >= 3) __builtin_amdgcn_s_sleep(1);
        }
      }
    }
    __syncthreads();
  }
}

extern "C" void kernel_launch(void* const* d_in, const int* in_sizes, int n_in,
                              void* d_out, int out_size, void* d_ws, size_t ws_size,
                              hipStream_t stream) {
  uint* ws = (uint*)d_ws;
  // ws layout (u32): h0g[2][128][200] @0, h1g[2][128][200] @51200,
  // flags (512 u32) @102400. Footprint identical to proven R3/R8/R13.
  hipMemsetAsync(d_ws, 0, (size_t)(102400 + 512) * sizeof(uint), stream);
  gru2_mfma<<<128, 256, 0, stream>>>(
      (const float*)d_in[0],
      (const float*)d_in[1], (const float*)d_in[2],
      (const float*)d_in[3], (const float*)d_in[4],
      (const float*)d_in[5], (const float*)d_in[6],
      (const float*)d_in[7], (const float*)d_in[8],
      (const float*)d_in[9], (const float*)d_in[10],
      (float*)d_out, ws, ws + 51200, ws + 102400);
}